// Round 15
// baseline (63.718 us; speedup 1.0000x reference)
//
#include <hip/hip_runtime.h>
#include <hip/hip_bf16.h>

#define NN 512
#define FIN 128
#define HH 4
#define DD 64
#define SW 68   // permuted/padded e-width: 17 groups x 4
#define REP 2   // measurement: repeat attn hot loop (idempotent) to surface counters
// lrelu(z) = 0.6*z + 0.4*|z|; a.lrelu folded: 0.6*(a.zi+a.zj) + sum_g sgn_g*|azi+azj|

// ws layout (floats):
//  h_ws   [8][512][64]         262144  @ 0
//  azi_ws [8][512][68]         278528  @ 262144
//  azj_ws [8][512][68]         278528  @ 540672
//  adi_ws [8][512]             4096    @ 819200
//  adj_ws [8][512]             4096    @ 823296
//  pacc   [16][8][512][64]     4194304 @ 827392
//  pm     [16][4096]           65536   @ 5021696
//  ps     [16][4096]           65536   @ 5087232

// ---------------------------------------------------------------------------
// proj: unchanged (validated r12-r14). 512 blocks x 256.
// ---------------------------------------------------------------------------
__global__ __launch_bounds__(256) void proj_kernel(
    const float* __restrict__ x, const float* __restrict__ Wp,
    const float* __restrict__ bp, const float* __restrict__ Wc,
    const float* __restrict__ Wcb, const float* __restrict__ a,
    float* __restrict__ h_ws, float* __restrict__ azi_ws, float* __restrict__ azj_ws,
    float* __restrict__ adi_ws, float* __restrict__ adj_ws)
{
    int blk = blockIdx.x;
    int bh = blk >> 6;
    int n0 = (blk & 63) << 3;
    int b = bh >> 2, hh = bh & 3;

    __shared__ float xs[8 * FIN];
    __shared__ float hs[8][DD];
    __shared__ float Wcs[DD][2 * DD + 1];

    int t = threadIdx.x;

    ((float4*)xs)[t] = ((const float4*)(x + ((size_t)b * NN + n0) * FIN))[t];
    {
        const float4* wg = (const float4*)(Wc + (size_t)hh * DD * 2 * DD);
        #pragma unroll
        for (int k = 0; k < 8; ++k) {
            int idx = t + 256 * k;
            int r = idx >> 5, c4 = (idx & 31) * 4;
            float4 v = wg[idx];
            Wcs[r][c4] = v.x; Wcs[r][c4 + 1] = v.y;
            Wcs[r][c4 + 2] = v.z; Wcs[r][c4 + 3] = v.w;
        }
    }
    __syncthreads();

    int e = t & 63, w = t >> 6;            // rows w, w+4
    const float* Wph = Wp + (size_t)hh * FIN * DD;
    float bpv = bp[hh * DD + e];
    float acc0 = bpv, acc1 = bpv;
    #pragma unroll 8
    for (int i = 0; i < FIN; ++i) {
        float wv = Wph[i * DD + e];
        acc0 = fmaf(xs[w * FIN + i], wv, acc0);
        acc1 = fmaf(xs[(w + 4) * FIN + i], wv, acc1);
    }
    hs[w][e] = acc0; hs[w + 4][e] = acc1;
    float* hg = h_ws + ((size_t)bh * NN + n0) * DD;
    hg[w * DD + e] = acc0; hg[(w + 4) * DD + e] = acc1;
    __syncthreads();

    float zb = Wcb[hh * DD + e];
    float zi0 = zb, zi1 = zb, zj0 = 0.f, zj1 = 0.f;
    #pragma unroll 8
    for (int d2 = 0; d2 < DD; ++d2) {
        float w1 = Wcs[e][d2];
        float w2 = Wcs[e][DD + d2];
        float h0 = hs[w][d2], h1 = hs[w + 4][d2];
        zi0 = fmaf(h0, w1, zi0); zi1 = fmaf(h1, w1, zi1);
        zj0 = fmaf(h0, w2, zj0); zj1 = fmaf(h1, w2, zj1);
    }

    float av = a[hh * DD + e];
    float p0 = av * zi0, p1 = av * zi1, q0 = av * zj0, q1 = av * zj1;
    #pragma unroll
    for (int off = 32; off; off >>= 1) {
        p0 += __shfl_xor(p0, off); p1 += __shfl_xor(p1, off);
        q0 += __shfl_xor(q0, off); q1 += __shfl_xor(q1, off);
    }
    if (e == 0) {
        adi_ws[bh * NN + n0 + w]     = 0.6f * p0;
        adi_ws[bh * NN + n0 + w + 4] = 0.6f * p1;
        adj_ws[bh * NN + n0 + w]     = 0.6f * q0;
        adj_ws[bh * NN + n0 + w + 4] = 0.6f * q1;
    }

    unsigned long long mask = __ballot(av >= 0.f);
    int np = __popcll(mask);
    int GP = (np + 3) >> 2;
    int below = __popcll(mask & ((1ull << e) - 1ull));
    int slot = (av >= 0.f) ? below : (4 * GP + (e - below));
    float pav = __builtin_fabsf(av);

    float* azib = azi_ws + ((size_t)bh * NN + n0) * SW;
    float* azjb = azj_ws + ((size_t)bh * NN + n0) * SW;
    azib[w * SW + slot]       = pav * zi0;
    azib[(w + 4) * SW + slot] = pav * zi1;
    azjb[w * SW + slot]       = pav * zj0;
    azjb[(w + 4) * SW + slot] = pav * zj1;
    int p1c = 4 * GP - np;
    if (e < 4) {
        int psl = (e < p1c) ? (np + e) : (4 * GP + 64 - np + (e - p1c));
        azib[w * SW + psl] = 0.f; azib[(w + 4) * SW + psl] = 0.f;
        azjb[w * SW + psl] = 0.f; azjb[(w + 4) * SW + psl] = 0.f;
    }
}

// ---------------------------------------------------------------------------
// attn6 + REP: identical structure to r14, hot phases repeated REP times
// (idempotent: every rep fully rewrites eP, pm/ps, pacc with same values).
// grid = 8bh x 8is x 16js = 1024 blocks x 256 thr.
// ---------------------------------------------------------------------------
#define AZJ 0        // [32][68] floats in smA
#define HT  2176     // [32][64]
#define ADJ 4224     // [32]
__global__ __launch_bounds__(256) void attn6(
    const float* __restrict__ h_ws, const float* __restrict__ azi_ws,
    const float* __restrict__ azj_ws, const float* __restrict__ adi_ws,
    const float* __restrict__ adj_ws, const float* __restrict__ a,
    float* __restrict__ pacc, float* __restrict__ pm, float* __restrict__ ps)
{
    int blk = blockIdx.x;
    int js = blk & 15, is_ = (blk >> 4) & 7, bh = blk >> 7;
    int i0 = is_ << 6, j0 = js << 5, hh = bh & 3;
    int t = threadIdx.x, lane = t & 63, w = t >> 6;

    __shared__ float smA[64 * 68];   // 17.4 KB: azi staging, then azj+h+adj
    __shared__ float eP[32 * 68];    // 8.7 KB: e then p, [j][i(+pad)]

    // ---- stage azi strip [64][68] (coalesced), then own row -> regs ----
    {
        const float4* src = (const float4*)(azi_ws + ((size_t)bh * NN + i0) * SW);
        float4* dst = (float4*)smA;
        #pragma unroll
        for (int k = 0; k < 5; ++k) {
            int idx = t + 256 * k;
            if (idx < 1088) dst[idx] = src[idx];
        }
    }
    __syncthreads();
    float4 azi4[17];
    #pragma unroll
    for (int k = 0; k < 17; ++k)
        azi4[k] = *(const float4*)&smA[lane * SW + 4 * k];
    float adiv = adi_ws[bh * NN + i0 + lane];
    __syncthreads();                 // azi staging region free

    // ---- stage azj [32][68] + h [32][64] + adj [32] (coalesced) ----
    {
        const float4* sj = (const float4*)(azj_ws + ((size_t)bh * NN + j0) * SW);
        #pragma unroll
        for (int k = 0; k < 3; ++k) {
            int idx = t + 256 * k;
            if (idx < 544) ((float4*)&smA[AZJ])[idx] = sj[idx];
        }
        const float4* sh = (const float4*)(h_ws + ((size_t)bh * NN + j0) * DD);
        ((float4*)&smA[HT])[t]       = sh[t];
        ((float4*)&smA[HT])[t + 256] = sh[t + 256];
        if (t < 32) smA[ADJ + t] = adj_ws[bh * NN + j0 + t];
    }

    float av_e = a[hh * DD + lane];
    unsigned long long mask = __ballot(av_e >= 0.f);
    int GP = (__popcll(mask) + 3) >> 2;

    for (int rep = 0; rep < REP; ++rep) {
        __syncthreads();             // staging ready / prev-rep phase3 done

        // ---- phase 1: scores. wave w does j = 8w..8w+7, lane = i ----
        #pragma unroll
        for (int jj = 0; jj < 8; ++jj) {
            int j = 8 * w + jj;
            const float4* aj = (const float4*)&smA[AZJ + j * SW];   // uniform
            float adjv = smA[ADJ + j];                              // uniform
            float c0 = 0.f, c1 = 0.f, c2 = 0.f, c3 = 0.f;
            #pragma unroll
            for (int k = 0; k < 17; ++k) {
                float4 A = aj[k];
                float sg = (k < GP) ? 0.4f : -0.4f;
                c0 = fmaf(sg, __builtin_fabsf(azi4[k].x + A.x), c0);
                c1 = fmaf(sg, __builtin_fabsf(azi4[k].y + A.y), c1);
                c2 = fmaf(sg, __builtin_fabsf(azi4[k].z + A.z), c2);
                c3 = fmaf(sg, __builtin_fabsf(azi4[k].w + A.w), c3);
            }
            eP[j * SW + lane] = adiv + adjv + ((c0 + c1) + (c2 + c3));
        }
        __syncthreads();

        // ---- phase 2: softmax. lane (il, jq): row iL = 16w + il ----
        {
            int il = lane & 15, jq = lane >> 4;
            int iL = 16 * w + il;
            float e8[8];
            float m = -1e30f;
            #pragma unroll
            for (int jj = 0; jj < 8; ++jj) {
                e8[jj] = eP[(jq * 8 + jj) * SW + iL];
                m = fmaxf(m, e8[jj]);
            }
            m = fmaxf(m, __shfl_xor(m, 16));
            m = fmaxf(m, __shfl_xor(m, 32));
            float s = 0.f;
            #pragma unroll
            for (int jj = 0; jj < 8; ++jj) {
                float p = __expf(e8[jj] - m);
                s += p;
                eP[(jq * 8 + jj) * SW + iL] = p;
            }
            s += __shfl_xor(s, 16);
            s += __shfl_xor(s, 32);
            if (jq == 0) {
                pm[js * 4096 + bh * NN + i0 + iL] = m;
                ps[js * 4096 + bh * NN + i0 + iL] = s;
            }
        }
        __syncthreads();

        // ---- phase 3: PV. wave w: i = 16w..16w+15, lane = d ----
        float acc[16];
        #pragma unroll
        for (int ii = 0; ii < 16; ++ii) acc[ii] = 0.f;
        #pragma unroll 8
        for (int j = 0; j < 32; ++j) {
            float hv = smA[HT + j * 64 + lane];                     // per-lane b32
            const float4* pp = (const float4*)&eP[j * SW + 16 * w]; // uniform b128
            float4 p0 = pp[0], p1 = pp[1], p2 = pp[2], p3 = pp[3];
            acc[0]  = fmaf(p0.x, hv, acc[0]);  acc[1]  = fmaf(p0.y, hv, acc[1]);
            acc[2]  = fmaf(p0.z, hv, acc[2]);  acc[3]  = fmaf(p0.w, hv, acc[3]);
            acc[4]  = fmaf(p1.x, hv, acc[4]);  acc[5]  = fmaf(p1.y, hv, acc[5]);
            acc[6]  = fmaf(p1.z, hv, acc[6]);  acc[7]  = fmaf(p1.w, hv, acc[7]);
            acc[8]  = fmaf(p2.x, hv, acc[8]);  acc[9]  = fmaf(p2.y, hv, acc[9]);
            acc[10] = fmaf(p2.z, hv, acc[10]); acc[11] = fmaf(p2.w, hv, acc[11]);
            acc[12] = fmaf(p3.x, hv, acc[12]); acc[13] = fmaf(p3.y, hv, acc[13]);
            acc[14] = fmaf(p3.z, hv, acc[14]); acc[15] = fmaf(p3.w, hv, acc[15]);
        }

        // ---- store partials (coalesced: lane = d), same values every rep ----
        float* pb = pacc + ((size_t)(js * 8 + bh) * NN + i0 + 16 * w) * DD + lane;
        #pragma unroll
        for (int ii = 0; ii < 16; ++ii)
            pb[(size_t)ii * DD] = acc[ii];
    }
}

// ---------------------------------------------------------------------------
// combine 16 j-splits + bias (validated r12-r14). grid = 1024 x 256.
// ---------------------------------------------------------------------------
__global__ __launch_bounds__(256) void combine_kernel(
    const float* __restrict__ pacc, const float* __restrict__ pm,
    const float* __restrict__ ps, const float* __restrict__ bias_param,
    float* __restrict__ out)
{
    int tid = blockIdx.x * 256 + threadIdx.x;
    int d = tid & 63;
    int row = tid >> 6;
    int bh = row >> 9, n = row & 511;
    int b = bh >> 2, hh = bh & 3;
    float mv[16];
    float m = -1e30f;
    #pragma unroll
    for (int p = 0; p < 16; ++p) { mv[p] = pm[p * 4096 + row]; m = fmaxf(m, mv[p]); }
    float denom = 0.f, acc = 0.f;
    #pragma unroll
    for (int p = 0; p < 16; ++p) {
        float wgt = __expf(mv[p] - m);
        denom = fmaf(ps[p * 4096 + row], wgt, denom);
        acc = fmaf(pacc[(size_t)p * 262144 + (size_t)row * 64 + d], wgt, acc);
    }
    out[((size_t)b * NN + n) * (HH * DD) + hh * DD + d] =
        acc / denom + bias_param[hh * DD + d];
}

extern "C" void kernel_launch(void* const* d_in, const int* in_sizes, int n_in,
                              void* d_out, int out_size, void* d_ws, size_t ws_size,
                              hipStream_t stream) {
    const float* x    = (const float*)d_in[0];
    const float* Wp   = (const float*)d_in[1];
    const float* bp   = (const float*)d_in[2];
    const float* Wc   = (const float*)d_in[3];
    const float* Wcb  = (const float*)d_in[4];
    const float* a    = (const float*)d_in[5];
    const float* bpar = (const float*)d_in[6];
    float* out = (float*)d_out;

    float* ws     = (float*)d_ws;
    float* h_ws   = ws;
    float* azi_ws = ws + 262144;
    float* azj_ws = ws + 540672;
    float* adi_ws = ws + 819200;
    float* adj_ws = ws + 823296;
    float* pacc   = ws + 827392;
    float* pm     = ws + 5021696;
    float* ps     = ws + 5087232;

    proj_kernel<<<dim3(512), dim3(256), 0, stream>>>(
        x, Wp, bp, Wc, Wcb, a, h_ws, azi_ws, azj_ws, adi_ws, adj_ws);
    attn6<<<dim3(1024), dim3(256), 0, stream>>>(
        h_ws, azi_ws, azj_ws, adi_ws, adj_ws, a, pacc, pm, ps);
    combine_kernel<<<dim3(1024), dim3(256), 0, stream>>>(
        pacc, pm, ps, bpar, out);
}

// Round 16
// 54.055 us; speedup vs baseline: 1.1788x; 1.1788x over previous
//
#include <hip/hip_runtime.h>
#include <hip/hip_bf16.h>

#define NN 512
#define FIN 128
#define HH 4
#define DD 64
// lrelu(z) = 0.6*z + 0.4*|z|
// e_ij = adi_i + adj_j + sum_k u_k*|zi_ik + zj_jk|,  u = 0.4*a

// ws layout (floats):
//  h_ws   [8][512][64]      262144  @ 0
//  zi_ws  [8][512][64]      262144  @ 262144   (zi' = h@W1^T + Wcb)
//  zj_ws  [8][512][64]      262144  @ 524288
//  adi_ws [8][512]          4096    @ 786432   (0.6 * sum a*zi')
//  adj_ws [8][512]          4096    @ 790528
//  pacc   [16][8][512][64]  4194304 @ 794624
//  pm     [16][4096]        65536   @ 4988928
//  ps     [16][4096]        65536   @ 5054464

__device__ __forceinline__ float rdlane(float v, int idx) {
    return __int_as_float(__builtin_amdgcn_readlane(__float_as_int(v), idx));
}

// ---------------------------------------------------------------------------
// proj: h = x@Wp+bp ; zi' = h@W1^T+Wcb ; zj = h@W2^T ; adi/adj dots.
// (r14 proj minus all permutation machinery.) 512 blocks x 256.
// ---------------------------------------------------------------------------
__global__ __launch_bounds__(256) void proj_kernel(
    const float* __restrict__ x, const float* __restrict__ Wp,
    const float* __restrict__ bp, const float* __restrict__ Wc,
    const float* __restrict__ Wcb, const float* __restrict__ a,
    float* __restrict__ h_ws, float* __restrict__ zi_ws, float* __restrict__ zj_ws,
    float* __restrict__ adi_ws, float* __restrict__ adj_ws)
{
    int blk = blockIdx.x;
    int bh = blk >> 6;
    int n0 = (blk & 63) << 3;
    int b = bh >> 2, hh = bh & 3;

    __shared__ float xs[8 * FIN];
    __shared__ float hs[8][DD];
    __shared__ float Wcs[DD][2 * DD + 1];

    int t = threadIdx.x;

    ((float4*)xs)[t] = ((const float4*)(x + ((size_t)b * NN + n0) * FIN))[t];
    {
        const float4* wg = (const float4*)(Wc + (size_t)hh * DD * 2 * DD);
        #pragma unroll
        for (int k = 0; k < 8; ++k) {
            int idx = t + 256 * k;
            int r = idx >> 5, c4 = (idx & 31) * 4;
            float4 v = wg[idx];
            Wcs[r][c4] = v.x; Wcs[r][c4 + 1] = v.y;
            Wcs[r][c4 + 2] = v.z; Wcs[r][c4 + 3] = v.w;
        }
    }
    __syncthreads();

    int e = t & 63, w = t >> 6;            // rows w, w+4
    const float* Wph = Wp + (size_t)hh * FIN * DD;
    float bpv = bp[hh * DD + e];
    float acc0 = bpv, acc1 = bpv;
    #pragma unroll 8
    for (int i = 0; i < FIN; ++i) {
        float wv = Wph[i * DD + e];
        acc0 = fmaf(xs[w * FIN + i], wv, acc0);
        acc1 = fmaf(xs[(w + 4) * FIN + i], wv, acc1);
    }
    hs[w][e] = acc0; hs[w + 4][e] = acc1;
    float* hg = h_ws + ((size_t)bh * NN + n0) * DD;
    hg[w * DD + e] = acc0; hg[(w + 4) * DD + e] = acc1;
    __syncthreads();

    float zb = Wcb[hh * DD + e];
    float zi0 = zb, zi1 = zb, zj0 = 0.f, zj1 = 0.f;
    #pragma unroll 8
    for (int d2 = 0; d2 < DD; ++d2) {
        float w1 = Wcs[e][d2];
        float w2 = Wcs[e][DD + d2];
        float h0 = hs[w][d2], h1 = hs[w + 4][d2];
        zi0 = fmaf(h0, w1, zi0); zi1 = fmaf(h1, w1, zi1);
        zj0 = fmaf(h0, w2, zj0); zj1 = fmaf(h1, w2, zj1);
    }

    float* zib = zi_ws + ((size_t)bh * NN + n0) * DD;
    float* zjb = zj_ws + ((size_t)bh * NN + n0) * DD;
    zib[w * DD + e] = zi0; zib[(w + 4) * DD + e] = zi1;
    zjb[w * DD + e] = zj0; zjb[(w + 4) * DD + e] = zj1;

    float av = a[hh * DD + e];
    float p0 = av * zi0, p1 = av * zi1, q0 = av * zj0, q1 = av * zj1;
    #pragma unroll
    for (int off = 32; off; off >>= 1) {
        p0 += __shfl_xor(p0, off); p1 += __shfl_xor(p1, off);
        q0 += __shfl_xor(q0, off); q1 += __shfl_xor(q1, off);
    }
    if (e == 0) {
        adi_ws[bh * NN + n0 + w]     = 0.6f * p0;
        adi_ws[bh * NN + n0 + w + 4] = 0.6f * p1;
        adj_ws[bh * NN + n0 + w]     = 0.6f * q0;
        adj_ws[bh * NN + n0 + w + 4] = 0.6f * q1;
    }
}

// ---------------------------------------------------------------------------
// attn7: [64 i][32 j] tiles; shared operands via v_readlane (VALU pipe),
// NOT LDS broadcast. LDS only for the 8.3 KB eP buffer. 2 barriers.
// grid = 8bh x 8is x 16js = 1024 blocks x 256 thr.
// ---------------------------------------------------------------------------
__global__ __launch_bounds__(256) void attn7(
    const float* __restrict__ h_ws, const float* __restrict__ zi_ws,
    const float* __restrict__ zj_ws, const float* __restrict__ adi_ws,
    const float* __restrict__ adj_ws, const float* __restrict__ a,
    float* __restrict__ pacc, float* __restrict__ pm, float* __restrict__ ps)
{
    int blk = blockIdx.x;
    int js = blk & 15, is_ = (blk >> 4) & 7, bh = blk >> 7;
    int i0 = is_ << 6, j0 = js << 5, hh = bh & 3;
    int t = threadIdx.x, lane = t & 63, w = t >> 6;

    __shared__ float eP[32 * 65];   // 8.3 KB; stride 65 -> conflict-free b32

    // per-lane zi row (lane = i): 16 x dwordx4, one-time, L2-hot
    float4 zi4[16];
    {
        const float4* zr = (const float4*)(zi_ws + ((size_t)bh * NN + i0 + lane) * DD);
        #pragma unroll
        for (int k = 0; k < 16; ++k) zi4[k] = zr[k];
    }
    float vu   = 0.4f * a[hh * DD + lane];            // lane = k holder
    float vadj = adj_ws[bh * NN + j0 + (lane & 31)];  // lane = j holder
    float vadi = adi_ws[bh * NN + i0 + lane];

    // ---- phase 1: scores. wave w -> j = 8w..8w+7; lane = i ----
    #pragma unroll
    for (int jj = 0; jj < 8; ++jj) {
        int j = 8 * w + jj;
        float vzj = zj_ws[((size_t)bh * NN + j0 + j) * DD + lane];  // coalesced
        float sadj = rdlane(vadj, j);
        float a0 = 0.f, a1 = 0.f, a2 = 0.f, a3 = 0.f;
        #pragma unroll
        for (int k = 0; k < 16; ++k) {
            float4 z = zi4[k];
            float s0 = rdlane(vzj, 4 * k + 0), u0 = rdlane(vu, 4 * k + 0);
            float s1 = rdlane(vzj, 4 * k + 1), u1 = rdlane(vu, 4 * k + 1);
            float s2 = rdlane(vzj, 4 * k + 2), u2 = rdlane(vu, 4 * k + 2);
            float s3 = rdlane(vzj, 4 * k + 3), u3 = rdlane(vu, 4 * k + 3);
            a0 = fmaf(u0, __builtin_fabsf(z.x + s0), a0);
            a1 = fmaf(u1, __builtin_fabsf(z.y + s1), a1);
            a2 = fmaf(u2, __builtin_fabsf(z.z + s2), a2);
            a3 = fmaf(u3, __builtin_fabsf(z.w + s3), a3);
        }
        eP[j * 65 + lane] = vadi + sadj + ((a0 + a1) + (a2 + a3));
    }
    __syncthreads();

    // ---- phase 2: softmax partial. lane (il, jq): row iL = 16w+il ----
    {
        int il = lane & 15, jq = lane >> 4;
        int iL = 16 * w + il;
        float e8[8];
        float m = -1e30f;
        #pragma unroll
        for (int jj = 0; jj < 8; ++jj) {
            e8[jj] = eP[(jq * 8 + jj) * 65 + iL];
            m = fmaxf(m, e8[jj]);
        }
        m = fmaxf(m, __shfl_xor(m, 16));
        m = fmaxf(m, __shfl_xor(m, 32));
        float s = 0.f;
        #pragma unroll
        for (int jj = 0; jj < 8; ++jj) {
            float p = __expf(e8[jj] - m);
            s += p;
            eP[(jq * 8 + jj) * 65 + iL] = p;
        }
        s += __shfl_xor(s, 16);
        s += __shfl_xor(s, 32);
        if (jq == 0) {
            pm[js * 4096 + bh * NN + i0 + iL] = m;
            ps[js * 4096 + bh * NN + i0 + iL] = s;
        }
    }
    __syncthreads();

    // ---- phase 3: PV. wave w: i = 16w..16w+15 (via readlane), lane = d ----
    float acc[16];
    #pragma unroll
    for (int ii = 0; ii < 16; ++ii) acc[ii] = 0.f;
    #pragma unroll 8
    for (int j = 0; j < 32; ++j) {
        float vh = h_ws[((size_t)bh * NN + j0 + j) * DD + lane];  // coalesced
        float vp = eP[j * 65 + lane];                             // lane = i
        #pragma unroll
        for (int ii = 0; ii < 16; ++ii) {
            float sp = rdlane(vp, 16 * w + ii);
            acc[ii] = fmaf(sp, vh, acc[ii]);
        }
    }

    float* pb = pacc + ((size_t)(js * 8 + bh) * NN + i0 + 16 * w) * DD + lane;
    #pragma unroll
    for (int ii = 0; ii < 16; ++ii)
        pb[(size_t)ii * DD] = acc[ii];
}

// ---------------------------------------------------------------------------
// combine 16 j-splits + bias (validated r12-r15). grid = 1024 x 256.
// ---------------------------------------------------------------------------
__global__ __launch_bounds__(256) void combine_kernel(
    const float* __restrict__ pacc, const float* __restrict__ pm,
    const float* __restrict__ ps, const float* __restrict__ bias_param,
    float* __restrict__ out)
{
    int tid = blockIdx.x * 256 + threadIdx.x;
    int d = tid & 63;
    int row = tid >> 6;
    int bh = row >> 9, n = row & 511;
    int b = bh >> 2, hh = bh & 3;
    float mv[16];
    float m = -1e30f;
    #pragma unroll
    for (int p = 0; p < 16; ++p) { mv[p] = pm[p * 4096 + row]; m = fmaxf(m, mv[p]); }
    float denom = 0.f, acc = 0.f;
    #pragma unroll
    for (int p = 0; p < 16; ++p) {
        float wgt = __expf(mv[p] - m);
        denom = fmaf(ps[p * 4096 + row], wgt, denom);
        acc = fmaf(pacc[(size_t)p * 262144 + (size_t)row * 64 + d], wgt, acc);
    }
    out[((size_t)b * NN + n) * (HH * DD) + hh * DD + d] =
        acc / denom + bias_param[hh * DD + d];
}

extern "C" void kernel_launch(void* const* d_in, const int* in_sizes, int n_in,
                              void* d_out, int out_size, void* d_ws, size_t ws_size,
                              hipStream_t stream) {
    const float* x    = (const float*)d_in[0];
    const float* Wp   = (const float*)d_in[1];
    const float* bp   = (const float*)d_in[2];
    const float* Wc   = (const float*)d_in[3];
    const float* Wcb  = (const float*)d_in[4];
    const float* a    = (const float*)d_in[5];
    const float* bpar = (const float*)d_in[6];
    float* out = (float*)d_out;

    float* ws     = (float*)d_ws;
    float* h_ws   = ws;
    float* zi_ws  = ws + 262144;
    float* zj_ws  = ws + 524288;
    float* adi_ws = ws + 786432;
    float* adj_ws = ws + 790528;
    float* pacc   = ws + 794624;
    float* pm     = ws + 4988928;
    float* ps     = ws + 5054464;

    proj_kernel<<<dim3(512), dim3(256), 0, stream>>>(
        x, Wp, bp, Wc, Wcb, a, h_ws, zi_ws, zj_ws, adi_ws, adj_ws);
    attn7<<<dim3(1024), dim3(256), 0, stream>>>(
        h_ws, zi_ws, zj_ws, adi_ws, adj_ws, a, pacc, pm, ps);
    combine_kernel<<<dim3(1024), dim3(256), 0, stream>>>(
        pacc, pm, ps, bpar, out);
}

// Round 17
// 53.158 us; speedup vs baseline: 1.1987x; 1.0169x over previous
//
#include <hip/hip_runtime.h>
#include <hip/hip_bf16.h>

#define NN 512
#define FIN 128
#define HH 4
#define DD 64
// lrelu(z) = 0.6*z + 0.4*|z|
// e_ij = adi_i + adj_j + sum_k u_k*|zi_ik + zj_jk|,  u = 0.4*a (signed)

// ws layout (floats):
//  h_ws   [8][512][64]      262144  @ 0
//  zi_ws  [8][512][64]      262144  @ 262144
//  zj_ws  [8][512][64]      262144  @ 524288
//  adi_ws [8][512]          4096    @ 786432
//  adj_ws [8][512]          4096    @ 790528
//  pacc   [16][8][512][64]  4194304 @ 794624
//  pm     [16][4096]        65536   @ 4988928
//  ps     [16][4096]        65536   @ 5054464
//  p_ws   [512][32][128]    2097152 @ 5120000   (block-local p slabs)

__device__ __forceinline__ float rdlane(float v, int idx) {
    return __int_as_float(__builtin_amdgcn_readlane(__float_as_int(v), idx));
}

// ---------------------------------------------------------------------------
// proj: h = x@Wp+bp ; zi' = h@W1^T+Wcb ; zj = h@W2^T ; adi/adj dots.
// (r16, validated.) 512 blocks x 256.
// ---------------------------------------------------------------------------
__global__ __launch_bounds__(256) void proj_kernel(
    const float* __restrict__ x, const float* __restrict__ Wp,
    const float* __restrict__ bp, const float* __restrict__ Wc,
    const float* __restrict__ Wcb, const float* __restrict__ a,
    float* __restrict__ h_ws, float* __restrict__ zi_ws, float* __restrict__ zj_ws,
    float* __restrict__ adi_ws, float* __restrict__ adj_ws)
{
    int blk = blockIdx.x;
    int bh = blk >> 6;
    int n0 = (blk & 63) << 3;
    int b = bh >> 2, hh = bh & 3;

    __shared__ float xs[8 * FIN];
    __shared__ float hs[8][DD];
    __shared__ float Wcs[DD][2 * DD + 1];

    int t = threadIdx.x;

    ((float4*)xs)[t] = ((const float4*)(x + ((size_t)b * NN + n0) * FIN))[t];
    {
        const float4* wg = (const float4*)(Wc + (size_t)hh * DD * 2 * DD);
        #pragma unroll
        for (int k = 0; k < 8; ++k) {
            int idx = t + 256 * k;
            int r = idx >> 5, c4 = (idx & 31) * 4;
            float4 v = wg[idx];
            Wcs[r][c4] = v.x; Wcs[r][c4 + 1] = v.y;
            Wcs[r][c4 + 2] = v.z; Wcs[r][c4 + 3] = v.w;
        }
    }
    __syncthreads();

    int e = t & 63, w = t >> 6;            // rows w, w+4
    const float* Wph = Wp + (size_t)hh * FIN * DD;
    float bpv = bp[hh * DD + e];
    float acc0 = bpv, acc1 = bpv;
    #pragma unroll 8
    for (int i = 0; i < FIN; ++i) {
        float wv = Wph[i * DD + e];
        acc0 = fmaf(xs[w * FIN + i], wv, acc0);
        acc1 = fmaf(xs[(w + 4) * FIN + i], wv, acc1);
    }
    hs[w][e] = acc0; hs[w + 4][e] = acc1;
    float* hg = h_ws + ((size_t)bh * NN + n0) * DD;
    hg[w * DD + e] = acc0; hg[(w + 4) * DD + e] = acc1;
    __syncthreads();

    float zb = Wcb[hh * DD + e];
    float zi0 = zb, zi1 = zb, zj0 = 0.f, zj1 = 0.f;
    #pragma unroll 8
    for (int d2 = 0; d2 < DD; ++d2) {
        float w1 = Wcs[e][d2];
        float w2 = Wcs[e][DD + d2];
        float h0 = hs[w][d2], h1 = hs[w + 4][d2];
        zi0 = fmaf(h0, w1, zi0); zi1 = fmaf(h1, w1, zi1);
        zj0 = fmaf(h0, w2, zj0); zj1 = fmaf(h1, w2, zj1);
    }

    float* zib = zi_ws + ((size_t)bh * NN + n0) * DD;
    float* zjb = zj_ws + ((size_t)bh * NN + n0) * DD;
    zib[w * DD + e] = zi0; zib[(w + 4) * DD + e] = zi1;
    zjb[w * DD + e] = zj0; zjb[(w + 4) * DD + e] = zj1;

    float av = a[hh * DD + e];
    float p0 = av * zi0, p1 = av * zi1, q0 = av * zj0, q1 = av * zj1;
    #pragma unroll
    for (int off = 32; off; off >>= 1) {
        p0 += __shfl_xor(p0, off); p1 += __shfl_xor(p1, off);
        q0 += __shfl_xor(q0, off); q1 += __shfl_xor(q1, off);
    }
    if (e == 0) {
        adi_ws[bh * NN + n0 + w]     = 0.6f * p0;
        adi_ws[bh * NN + n0 + w + 4] = 0.6f * p1;
        adj_ws[bh * NN + n0 + w]     = 0.6f * q0;
        adj_ws[bh * NN + n0 + w + 4] = 0.6f * q1;
    }
}

// ---------------------------------------------------------------------------
// attn8: tile [128 i][32 j], 512 blocks x 256 thr.
// Phase1: lane=i (2 rows), zj via uniform b128 LDS, u via SGPR (hoisted
// readlanes). Phase2: row-pair softmax, p -> global slab (coalesced).
// Phase3: lane=d, p via wave-uniform float4 global loads (L1-resident slab),
// h via per-lane LDS b32. 3 barriers.
// ---------------------------------------------------------------------------
__global__ __launch_bounds__(256) void attn8(
    const float* __restrict__ h_ws, const float* __restrict__ zi_ws,
    const float* __restrict__ zj_ws, const float* __restrict__ adi_ws,
    const float* __restrict__ adj_ws, const float* __restrict__ a,
    float* __restrict__ pacc, float* __restrict__ pm, float* __restrict__ ps,
    float* __restrict__ p_ws)
{
    int blk = blockIdx.x;
    int js = blk & 15, is_ = (blk >> 4) & 3, bh = blk >> 6;
    int i0 = is_ << 7, j0 = js << 5, hh = bh & 3;
    int t = threadIdx.x, lane = t & 63;
    int wid = __builtin_amdgcn_readfirstlane(t >> 6);

    __shared__ float smZJ[32 * 64];    // 8 KB
    __shared__ float smH[32 * 64];     // 8 KB
    __shared__ float eL[32 * 129];     // 16.1 KB

    // zi rows (lane, lane+64) direct from global (L2-hot, one-time)
    float4 ziA[16], ziB[16];
    {
        const float4* zr0 = (const float4*)(zi_ws + ((size_t)bh * NN + i0 + lane) * DD);
        const float4* zr1 = (const float4*)(zi_ws + ((size_t)bh * NN + i0 + 64 + lane) * DD);
        #pragma unroll
        for (int k = 0; k < 16; ++k) { ziA[k] = zr0[k]; ziB[k] = zr1[k]; }
    }

    // stage zj + h tiles (coalesced)
    {
        const float4* sj = (const float4*)(zj_ws + ((size_t)bh * NN + j0) * DD);
        const float4* sh = (const float4*)(h_ws + ((size_t)bh * NN + j0) * DD);
        ((float4*)smZJ)[t] = sj[t];
        ((float4*)smZJ)[t + 256] = sj[t + 256];
        ((float4*)smH)[t] = sh[t];
        ((float4*)smH)[t + 256] = sh[t + 256];
    }

    // u = 0.4*a -> 64 wave-uniform scalars (hoisted readlanes -> SGPRs)
    float vu = 0.4f * a[hh * DD + lane];
    float us[64];
    #pragma unroll
    for (int k = 0; k < 64; ++k) us[k] = rdlane(vu, k);

    // adj for this wave's 8 j (hoisted)
    float vadj = adj_ws[bh * NN + j0 + (lane & 31)];
    float adjS[8];
    #pragma unroll
    for (int jj = 0; jj < 8; ++jj) adjS[jj] = rdlane(vadj, 8 * wid + jj);

    float adi0 = adi_ws[bh * NN + i0 + lane];
    float adi1 = adi_ws[bh * NN + i0 + 64 + lane];

    __syncthreads();

    // ---- phase 1: scores. wave wid -> j = 8*wid..8*wid+7; lane = 2 i-rows ----
    #pragma unroll
    for (int jj = 0; jj < 8; ++jj) {
        int j = 8 * wid + jj;
        const float4* zjr = (const float4*)(smZJ + j * 64);   // uniform b128
        float a0 = 0.f, a1 = 0.f, b0 = 0.f, b1 = 0.f;
        #pragma unroll
        for (int k = 0; k < 16; ++k) {
            float4 z = zjr[k];
            float u0 = us[4 * k], u1 = us[4 * k + 1];
            float u2 = us[4 * k + 2], u3 = us[4 * k + 3];
            a0 = fmaf(u0, __builtin_fabsf(ziA[k].x + z.x), a0);
            a1 = fmaf(u1, __builtin_fabsf(ziA[k].y + z.y), a1);
            a0 = fmaf(u2, __builtin_fabsf(ziA[k].z + z.z), a0);
            a1 = fmaf(u3, __builtin_fabsf(ziA[k].w + z.w), a1);
            b0 = fmaf(u0, __builtin_fabsf(ziB[k].x + z.x), b0);
            b1 = fmaf(u1, __builtin_fabsf(ziB[k].y + z.y), b1);
            b0 = fmaf(u2, __builtin_fabsf(ziB[k].z + z.z), b0);
            b1 = fmaf(u3, __builtin_fabsf(ziB[k].w + z.w), b1);
        }
        eL[j * 129 + lane]      = adi0 + adjS[jj] + (a0 + a1);
        eL[j * 129 + 64 + lane] = adi1 + adjS[jj] + (b0 + b1);
    }
    __syncthreads();

    // ---- phase 2: softmax. thread-pair per row: r = t>>1, jh = t&1 ----
    {
        int r = t >> 1, jh = t & 1;
        float e16[16];
        float m = -1e30f;
        #pragma unroll
        for (int jj = 0; jj < 16; ++jj) {
            e16[jj] = eL[(16 * jh + jj) * 129 + r];
            m = fmaxf(m, e16[jj]);
        }
        m = fmaxf(m, __shfl_xor(m, 1));
        float s = 0.f;
        float* pb = p_ws + (size_t)blk * 4096 + 16 * jh * 128 + r;
        #pragma unroll
        for (int jj = 0; jj < 16; ++jj) {
            float p = __expf(e16[jj] - m);
            s += p;
            pb[jj * 128] = p;
        }
        s += __shfl_xor(s, 1);
        if (jh == 0) {
            pm[js * 4096 + bh * NN + i0 + r] = m;
            ps[js * 4096 + bh * NN + i0 + r] = s;
        }
    }
    __syncthreads();   // drains p stores (vmcnt) -> visible to phase 3

    // ---- phase 3: PV. wave wid -> i-rows 32*wid..+31; lane = d ----
    {
        int ib = 32 * wid;
        float acc[32];
        #pragma unroll
        for (int q = 0; q < 32; ++q) acc[q] = 0.f;
        const float* pbase = p_ws + (size_t)blk * 4096 + ib;
        #pragma unroll 4
        for (int j = 0; j < 32; ++j) {
            float hv = smH[j * 64 + lane];                        // 2-way, free
            const float4* pw = (const float4*)(pbase + j * 128);  // uniform
            #pragma unroll
            for (int q4 = 0; q4 < 8; ++q4) {
                float4 pv = pw[q4];
                acc[4 * q4 + 0] = fmaf(pv.x, hv, acc[4 * q4 + 0]);
                acc[4 * q4 + 1] = fmaf(pv.y, hv, acc[4 * q4 + 1]);
                acc[4 * q4 + 2] = fmaf(pv.z, hv, acc[4 * q4 + 2]);
                acc[4 * q4 + 3] = fmaf(pv.w, hv, acc[4 * q4 + 3]);
            }
        }
        float* ob = pacc + ((size_t)(js * 8 + bh) * NN + i0 + ib) * DD + lane;
        #pragma unroll
        for (int q = 0; q < 32; ++q)
            ob[(size_t)q * DD] = acc[q];
    }
}

// ---------------------------------------------------------------------------
// combine 16 j-splits + bias (validated r12-r16). grid = 1024 x 256.
// ---------------------------------------------------------------------------
__global__ __launch_bounds__(256) void combine_kernel(
    const float* __restrict__ pacc, const float* __restrict__ pm,
    const float* __restrict__ ps, const float* __restrict__ bias_param,
    float* __restrict__ out)
{
    int tid = blockIdx.x * 256 + threadIdx.x;
    int d = tid & 63;
    int row = tid >> 6;
    int bh = row >> 9, n = row & 511;
    int b = bh >> 2, hh = bh & 3;
    float mv[16];
    float m = -1e30f;
    #pragma unroll
    for (int p = 0; p < 16; ++p) { mv[p] = pm[p * 4096 + row]; m = fmaxf(m, mv[p]); }
    float denom = 0.f, acc = 0.f;
    #pragma unroll
    for (int p = 0; p < 16; ++p) {
        float wgt = __expf(mv[p] - m);
        denom = fmaf(ps[p * 4096 + row], wgt, denom);
        acc = fmaf(pacc[(size_t)p * 262144 + (size_t)row * 64 + d], wgt, acc);
    }
    out[((size_t)b * NN + n) * (HH * DD) + hh * DD + d] =
        acc / denom + bias_param[hh * DD + d];
}

extern "C" void kernel_launch(void* const* d_in, const int* in_sizes, int n_in,
                              void* d_out, int out_size, void* d_ws, size_t ws_size,
                              hipStream_t stream) {
    const float* x    = (const float*)d_in[0];
    const float* Wp   = (const float*)d_in[1];
    const float* bp   = (const float*)d_in[2];
    const float* Wc   = (const float*)d_in[3];
    const float* Wcb  = (const float*)d_in[4];
    const float* a    = (const float*)d_in[5];
    const float* bpar = (const float*)d_in[6];
    float* out = (float*)d_out;

    float* ws     = (float*)d_ws;
    float* h_ws   = ws;
    float* zi_ws  = ws + 262144;
    float* zj_ws  = ws + 524288;
    float* adi_ws = ws + 786432;
    float* adj_ws = ws + 790528;
    float* pacc   = ws + 794624;
    float* pm     = ws + 4988928;
    float* ps     = ws + 5054464;
    float* p_ws   = ws + 5120000;

    proj_kernel<<<dim3(512), dim3(256), 0, stream>>>(
        x, Wp, bp, Wc, Wcb, a, h_ws, zi_ws, zj_ws, adi_ws, adj_ws);
    attn8<<<dim3(512), dim3(256), 0, stream>>>(
        h_ws, zi_ws, zj_ws, adi_ws, adj_ws, a, pacc, pm, ps, p_ws);
    combine_kernel<<<dim3(1024), dim3(256), 0, stream>>>(
        pacc, pm, ps, bpar, out);
}

// Round 18
// 48.747 us; speedup vs baseline: 1.3071x; 1.0905x over previous
//
#include <hip/hip_runtime.h>
#include <hip/hip_bf16.h>

#define NN 512
#define FIN 128
#define HH 4
#define DD 64
#define SW 68   // permuted/padded e-width: 17 groups x 4
// lrelu(z) = 0.6*z + 0.4*|z|; folded: 0.6*(a.zi+a.zj) + sum_g sgn_g*|azi+azj|

// ws layout (floats):
//  h_ws   [8][512][64]         262144  @ 0
//  azi_ws [8][512][68]         278528  @ 262144   (|a|-scaled, permuted, +Wcb)
//  azj_ws [8][512][68]         278528  @ 540672
//  adi_ws [8][512]             4096    @ 819200
//  adj_ws [8][512]             4096    @ 823296
//  pacc   [16][8][512][64]     4194304 @ 827392
//  pm     [16][4096]           65536   @ 5021696
//  ps     [16][4096]           65536   @ 5087232

__device__ __forceinline__ float rdlane(float v, int idx) {
    return __int_as_float(__builtin_amdgcn_readlane(__float_as_int(v), idx));
}

// ---------------------------------------------------------------------------
// proj: r14 version (permuted azi/azj scatter) — validated. 512 blocks x 256.
// ---------------------------------------------------------------------------
__global__ __launch_bounds__(256) void proj_kernel(
    const float* __restrict__ x, const float* __restrict__ Wp,
    const float* __restrict__ bp, const float* __restrict__ Wc,
    const float* __restrict__ Wcb, const float* __restrict__ a,
    float* __restrict__ h_ws, float* __restrict__ azi_ws, float* __restrict__ azj_ws,
    float* __restrict__ adi_ws, float* __restrict__ adj_ws)
{
    int blk = blockIdx.x;
    int bh = blk >> 6;
    int n0 = (blk & 63) << 3;
    int b = bh >> 2, hh = bh & 3;

    __shared__ float xs[8 * FIN];
    __shared__ float hs[8][DD];
    __shared__ float Wcs[DD][2 * DD + 1];

    int t = threadIdx.x;

    ((float4*)xs)[t] = ((const float4*)(x + ((size_t)b * NN + n0) * FIN))[t];
    {
        const float4* wg = (const float4*)(Wc + (size_t)hh * DD * 2 * DD);
        #pragma unroll
        for (int k = 0; k < 8; ++k) {
            int idx = t + 256 * k;
            int r = idx >> 5, c4 = (idx & 31) * 4;
            float4 v = wg[idx];
            Wcs[r][c4] = v.x; Wcs[r][c4 + 1] = v.y;
            Wcs[r][c4 + 2] = v.z; Wcs[r][c4 + 3] = v.w;
        }
    }
    __syncthreads();

    int e = t & 63, w = t >> 6;            // rows w, w+4
    const float* Wph = Wp + (size_t)hh * FIN * DD;
    float bpv = bp[hh * DD + e];
    float acc0 = bpv, acc1 = bpv;
    #pragma unroll 8
    for (int i = 0; i < FIN; ++i) {
        float wv = Wph[i * DD + e];
        acc0 = fmaf(xs[w * FIN + i], wv, acc0);
        acc1 = fmaf(xs[(w + 4) * FIN + i], wv, acc1);
    }
    hs[w][e] = acc0; hs[w + 4][e] = acc1;
    float* hg = h_ws + ((size_t)bh * NN + n0) * DD;
    hg[w * DD + e] = acc0; hg[(w + 4) * DD + e] = acc1;
    __syncthreads();

    float zb = Wcb[hh * DD + e];
    float zi0 = zb, zi1 = zb, zj0 = 0.f, zj1 = 0.f;
    #pragma unroll 8
    for (int d2 = 0; d2 < DD; ++d2) {
        float w1 = Wcs[e][d2];
        float w2 = Wcs[e][DD + d2];
        float h0 = hs[w][d2], h1 = hs[w + 4][d2];
        zi0 = fmaf(h0, w1, zi0); zi1 = fmaf(h1, w1, zi1);
        zj0 = fmaf(h0, w2, zj0); zj1 = fmaf(h1, w2, zj1);
    }

    float av = a[hh * DD + e];
    float p0 = av * zi0, p1 = av * zi1, q0 = av * zj0, q1 = av * zj1;
    #pragma unroll
    for (int off = 32; off; off >>= 1) {
        p0 += __shfl_xor(p0, off); p1 += __shfl_xor(p1, off);
        q0 += __shfl_xor(q0, off); q1 += __shfl_xor(q1, off);
    }
    if (e == 0) {
        adi_ws[bh * NN + n0 + w]     = 0.6f * p0;
        adi_ws[bh * NN + n0 + w + 4] = 0.6f * p1;
        adj_ws[bh * NN + n0 + w]     = 0.6f * q0;
        adj_ws[bh * NN + n0 + w + 4] = 0.6f * q1;
    }

    unsigned long long mask = __ballot(av >= 0.f);
    int np = __popcll(mask);
    int GP = (np + 3) >> 2;
    int below = __popcll(mask & ((1ull << e) - 1ull));
    int slot = (av >= 0.f) ? below : (4 * GP + (e - below));
    float pav = __builtin_fabsf(av);

    float* azib = azi_ws + ((size_t)bh * NN + n0) * SW;
    float* azjb = azj_ws + ((size_t)bh * NN + n0) * SW;
    azib[w * SW + slot]       = pav * zi0;
    azib[(w + 4) * SW + slot] = pav * zi1;
    azjb[w * SW + slot]       = pav * zj0;
    azjb[(w + 4) * SW + slot] = pav * zj1;
    int p1c = 4 * GP - np;
    if (e < 4) {
        int psl = (e < p1c) ? (np + e) : (4 * GP + 64 - np + (e - p1c));
        azib[w * SW + psl] = 0.f; azib[(w + 4) * SW + psl] = 0.f;
        azjb[w * SW + psl] = 0.f; azjb[(w + 4) * SW + psl] = 0.f;
    }
}

// ---------------------------------------------------------------------------
// attn9: tile [128 i][32 j]; phase1 = attn6-style with 2 i-rows/lane;
// phase3 = per-lane p read + readlane distribute (VALU pipe, not LDS b128).
// grid = 8bh x 4is x 16js = 512 blocks x 256 thr.
// ---------------------------------------------------------------------------
#define ZJS 0        // [32][68]
#define HS  2176     // [32][64]
#define ADJS 4224    // [32]
#define EPo 4256     // [32][132]
__global__ __launch_bounds__(256, 2) void attn9(
    const float* __restrict__ h_ws, const float* __restrict__ azi_ws,
    const float* __restrict__ azj_ws, const float* __restrict__ adi_ws,
    const float* __restrict__ adj_ws, const float* __restrict__ a,
    float* __restrict__ pacc, float* __restrict__ pm, float* __restrict__ ps)
{
    int blk = blockIdx.x;
    int js = blk & 15, is_ = (blk >> 4) & 3, bh = blk >> 6;
    int i0 = is_ << 7, j0 = js << 5, hh = bh & 3;
    int t = threadIdx.x, lane = t & 63;
    int w = __builtin_amdgcn_readfirstlane(t >> 6);

    __shared__ float smem[128 * 72];   // 36.9 KB; reused: azi-stage then zj+h+eP

    // ---- stage azi [128][68] -> [128][72] (coalesced), copy 2 rows to regs ----
    {
        const float4* src = (const float4*)(azi_ws + ((size_t)bh * NN + i0) * SW);
        #pragma unroll
        for (int k = 0; k < 9; ++k) {
            int idx = t + 256 * k;               // 2176 float4
            if (idx < 2176) {
                int r = idx / 17, c = idx % 17;
                *(float4*)&smem[r * 72 + c * 4] = src[idx];
            }
        }
    }
    __syncthreads();
    float4 ziA[17], ziB[17];
    #pragma unroll
    for (int k = 0; k < 17; ++k) {
        ziA[k] = *(const float4*)&smem[lane * 72 + 4 * k];
        ziB[k] = *(const float4*)&smem[(lane + 64) * 72 + 4 * k];
    }
    float adi0 = adi_ws[bh * NN + i0 + lane];
    float adi1 = adi_ws[bh * NN + i0 + 64 + lane];
    __syncthreads();                  // staging region free

    // ---- stage zj [32][68] + h [32][64] + adj [32] (coalesced) ----
    {
        const float4* sj = (const float4*)(azj_ws + ((size_t)bh * NN + j0) * SW);
        #pragma unroll
        for (int k = 0; k < 3; ++k) {
            int idx = t + 256 * k;
            if (idx < 544) ((float4*)&smem[ZJS])[idx] = sj[idx];
        }
        const float4* sh = (const float4*)(h_ws + ((size_t)bh * NN + j0) * DD);
        ((float4*)&smem[HS])[t] = sh[t];
        ((float4*)&smem[HS])[t + 256] = sh[t + 256];
        if (t < 32) smem[ADJS + t] = adj_ws[bh * NN + j0 + t];
    }

    float av_e = a[hh * DD + lane];
    unsigned long long mask = __ballot(av_e >= 0.f);
    int GP = (__popcll(mask) + 3) >> 2;

    __syncthreads();

    // ---- phase 1: scores. wave w -> j = 8w..8w+7; lane = i and i+64 ----
    #pragma unroll
    for (int jj = 0; jj < 8; ++jj) {
        int j = 8 * w + jj;
        const float4* zjr = (const float4*)&smem[ZJS + j * SW];   // uniform b128
        float adjv = smem[ADJS + j];
        float a0 = 0.f, a1 = 0.f, b0 = 0.f, b1 = 0.f;
        #pragma unroll
        for (int k = 0; k < 17; ++k) {
            float4 z = zjr[k];
            float sg = (k < GP) ? 0.4f : -0.4f;
            a0 = fmaf(sg, __builtin_fabsf(ziA[k].x + z.x), a0);
            a1 = fmaf(sg, __builtin_fabsf(ziA[k].y + z.y), a1);
            a0 = fmaf(sg, __builtin_fabsf(ziA[k].z + z.z), a0);
            a1 = fmaf(sg, __builtin_fabsf(ziA[k].w + z.w), a1);
            b0 = fmaf(sg, __builtin_fabsf(ziB[k].x + z.x), b0);
            b1 = fmaf(sg, __builtin_fabsf(ziB[k].y + z.y), b1);
            b0 = fmaf(sg, __builtin_fabsf(ziB[k].z + z.z), b0);
            b1 = fmaf(sg, __builtin_fabsf(ziB[k].w + z.w), b1);
        }
        smem[EPo + j * 132 + lane]      = adi0 + adjv + (a0 + a1);
        smem[EPo + j * 132 + 64 + lane] = adi1 + adjv + (b0 + b1);
    }
    __syncthreads();

    // ---- phase 2: softmax. 128 rows x 2 threads (jh halves of 32 j) ----
    {
        int r = t >> 1, jh = t & 1;
        float e16[16];
        float m = -1e30f;
        #pragma unroll
        for (int jj = 0; jj < 16; ++jj) {
            e16[jj] = smem[EPo + (16 * jh + jj) * 132 + r];
            m = fmaxf(m, e16[jj]);
        }
        m = fmaxf(m, __shfl_xor(m, 1));
        float s = 0.f;
        #pragma unroll
        for (int jj = 0; jj < 16; ++jj) {
            float p = __expf(e16[jj] - m);
            s += p;
            smem[EPo + (16 * jh + jj) * 132 + r] = p;
        }
        s += __shfl_xor(s, 1);
        if (jh == 0) {
            pm[js * 4096 + bh * NN + i0 + r] = m;
            ps[js * 4096 + bh * NN + i0 + r] = s;
        }
    }
    __syncthreads();

    // ---- phase 3: PV. wave w -> i = 32w..32w+31; lane = d.
    //      p via per-lane b32 + readlane (VALU), h via per-lane b32. ----
    {
        int hi = (w >> 1) * 64;          // 0 for w<2 (i 0..63), 64 for w>=2
        int base = (w & 1) * 32;         // lane offset within vp
        float acc[32];
        #pragma unroll
        for (int q = 0; q < 32; ++q) acc[q] = 0.f;
        #pragma unroll 4
        for (int j = 0; j < 32; ++j) {
            float vh = smem[HS + j * 64 + lane];            // per-lane b32
            float vp = smem[EPo + j * 132 + hi + lane];     // per-lane b32 (i=hi+lane)
            #pragma unroll
            for (int ii = 0; ii < 32; ++ii) {
                float sp = rdlane(vp, base + ii);           // VALU pipe
                acc[ii] = fmaf(sp, vh, acc[ii]);
            }
        }
        float* pb = pacc + ((size_t)(js * 8 + bh) * NN + i0 + 32 * w) * DD + lane;
        #pragma unroll
        for (int q = 0; q < 32; ++q)
            pb[(size_t)q * DD] = acc[q];
    }
}

// ---------------------------------------------------------------------------
// combine 16 j-splits + bias (validated r12-r17). grid = 1024 x 256.
// ---------------------------------------------------------------------------
__global__ __launch_bounds__(256) void combine_kernel(
    const float* __restrict__ pacc, const float* __restrict__ pm,
    const float* __restrict__ ps, const float* __restrict__ bias_param,
    float* __restrict__ out)
{
    int tid = blockIdx.x * 256 + threadIdx.x;
    int d = tid & 63;
    int row = tid >> 6;
    int bh = row >> 9, n = row & 511;
    int b = bh >> 2, hh = bh & 3;
    float mv[16];
    float m = -1e30f;
    #pragma unroll
    for (int p = 0; p < 16; ++p) { mv[p] = pm[p * 4096 + row]; m = fmaxf(m, mv[p]); }
    float denom = 0.f, acc = 0.f;
    #pragma unroll
    for (int p = 0; p < 16; ++p) {
        float wgt = __expf(mv[p] - m);
        denom = fmaf(ps[p * 4096 + row], wgt, denom);
        acc = fmaf(pacc[(size_t)p * 262144 + (size_t)row * 64 + d], wgt, acc);
    }
    out[((size_t)b * NN + n) * (HH * DD) + hh * DD + d] =
        acc / denom + bias_param[hh * DD + d];
}

extern "C" void kernel_launch(void* const* d_in, const int* in_sizes, int n_in,
                              void* d_out, int out_size, void* d_ws, size_t ws_size,
                              hipStream_t stream) {
    const float* x    = (const float*)d_in[0];
    const float* Wp   = (const float*)d_in[1];
    const float* bp   = (const float*)d_in[2];
    const float* Wc   = (const float*)d_in[3];
    const float* Wcb  = (const float*)d_in[4];
    const float* a    = (const float*)d_in[5];
    const float* bpar = (const float*)d_in[6];
    float* out = (float*)d_out;

    float* ws     = (float*)d_ws;
    float* h_ws   = ws;
    float* azi_ws = ws + 262144;
    float* azj_ws = ws + 540672;
    float* adi_ws = ws + 819200;
    float* adj_ws = ws + 823296;
    float* pacc   = ws + 827392;
    float* pm     = ws + 5021696;
    float* ps     = ws + 5087232;

    proj_kernel<<<dim3(512), dim3(256), 0, stream>>>(
        x, Wp, bp, Wc, Wcb, a, h_ws, azi_ws, azj_ws, adi_ws, adj_ws);
    attn9<<<dim3(512), dim3(256), 0, stream>>>(
        h_ws, azi_ws, azj_ws, adi_ws, adj_ws, a, pacc, pm, ps);
    combine_kernel<<<dim3(1024), dim3(256), 0, stream>>>(
        pacc, pm, ps, bpar, out);
}

// Round 19
// 44.868 us; speedup vs baseline: 1.4201x; 1.0865x over previous
//
#include <hip/hip_runtime.h>
#include <hip/hip_bf16.h>

#define NN 512
#define FIN 128
#define HH 4
#define DD 64
#define SW 68   // 17 chunks x 4 slots (sign-permuted, padded)
// lrelu(z) = 0.6*z + 0.4*|z|; folded: 0.6*(a.zi+a.zj) + sum_c sg_c*sum|azi+azj|

// ws layout (floats):
//  h_ws   [8][512][64]         262144  @ 0
//  azi_c  [8][17][512][4]      278528  @ 262144   (chunk-major, |a|-scaled, permuted)
//  azj_c  [8][17][512][4]      278528  @ 540672
//  adi_ws [8][512]             4096    @ 819200
//  adj_ws [8][512]             4096    @ 823296
//  pacc   [16][8][512][64]     4194304 @ 827392
//  pm     [16][4096]           65536   @ 5021696
//  ps     [16][4096]           65536   @ 5087232

__device__ __forceinline__ float rdlane(float v, int idx) {
    return __int_as_float(__builtin_amdgcn_readlane(__float_as_int(v), idx));
}

// ---------------------------------------------------------------------------
// proj: r14-validated math; azi/azj now written CHUNK-MAJOR. 512 blocks x 256.
// ---------------------------------------------------------------------------
__global__ __launch_bounds__(256) void proj_kernel(
    const float* __restrict__ x, const float* __restrict__ Wp,
    const float* __restrict__ bp, const float* __restrict__ Wc,
    const float* __restrict__ Wcb, const float* __restrict__ a,
    float* __restrict__ h_ws, float* __restrict__ azi_c, float* __restrict__ azj_c,
    float* __restrict__ adi_ws, float* __restrict__ adj_ws)
{
    int blk = blockIdx.x;
    int bh = blk >> 6;
    int n0 = (blk & 63) << 3;
    int b = bh >> 2, hh = bh & 3;

    __shared__ float xs[8 * FIN];
    __shared__ float hs[8][DD];
    __shared__ float Wcs[DD][2 * DD + 1];

    int t = threadIdx.x;

    ((float4*)xs)[t] = ((const float4*)(x + ((size_t)b * NN + n0) * FIN))[t];
    {
        const float4* wg = (const float4*)(Wc + (size_t)hh * DD * 2 * DD);
        #pragma unroll
        for (int k = 0; k < 8; ++k) {
            int idx = t + 256 * k;
            int r = idx >> 5, c4 = (idx & 31) * 4;
            float4 v = wg[idx];
            Wcs[r][c4] = v.x; Wcs[r][c4 + 1] = v.y;
            Wcs[r][c4 + 2] = v.z; Wcs[r][c4 + 3] = v.w;
        }
    }
    __syncthreads();

    int e = t & 63, w = t >> 6;            // rows w, w+4
    const float* Wph = Wp + (size_t)hh * FIN * DD;
    float bpv = bp[hh * DD + e];
    float acc0 = bpv, acc1 = bpv;
    #pragma unroll 8
    for (int i = 0; i < FIN; ++i) {
        float wv = Wph[i * DD + e];
        acc0 = fmaf(xs[w * FIN + i], wv, acc0);
        acc1 = fmaf(xs[(w + 4) * FIN + i], wv, acc1);
    }
    hs[w][e] = acc0; hs[w + 4][e] = acc1;
    float* hg = h_ws + ((size_t)bh * NN + n0) * DD;
    hg[w * DD + e] = acc0; hg[(w + 4) * DD + e] = acc1;
    __syncthreads();

    float zb = Wcb[hh * DD + e];
    float zi0 = zb, zi1 = zb, zj0 = 0.f, zj1 = 0.f;
    #pragma unroll 8
    for (int d2 = 0; d2 < DD; ++d2) {
        float w1 = Wcs[e][d2];
        float w2 = Wcs[e][DD + d2];
        float h0 = hs[w][d2], h1 = hs[w + 4][d2];
        zi0 = fmaf(h0, w1, zi0); zi1 = fmaf(h1, w1, zi1);
        zj0 = fmaf(h0, w2, zj0); zj1 = fmaf(h1, w2, zj1);
    }

    float av = a[hh * DD + e];
    float p0 = av * zi0, p1 = av * zi1, q0 = av * zj0, q1 = av * zj1;
    #pragma unroll
    for (int off = 32; off; off >>= 1) {
        p0 += __shfl_xor(p0, off); p1 += __shfl_xor(p1, off);
        q0 += __shfl_xor(q0, off); q1 += __shfl_xor(q1, off);
    }
    if (e == 0) {
        adi_ws[bh * NN + n0 + w]     = 0.6f * p0;
        adi_ws[bh * NN + n0 + w + 4] = 0.6f * p1;
        adj_ws[bh * NN + n0 + w]     = 0.6f * q0;
        adj_ws[bh * NN + n0 + w + 4] = 0.6f * q1;
    }

    unsigned long long mask = __ballot(av >= 0.f);
    int np = __popcll(mask);
    int GP = (np + 3) >> 2;
    int below = __popcll(mask & ((1ull << e) - 1ull));
    int slot = (av >= 0.f) ? below : (4 * GP + (e - below));
    float pav = __builtin_fabsf(av);

    // chunk-major writes: [bh][chunk][n][slot&3]
    {
        size_t a0 = ((size_t)(bh * 17 + (slot >> 2)) * NN + n0 + w) * 4 + (slot & 3);
        size_t a1 = ((size_t)(bh * 17 + (slot >> 2)) * NN + n0 + w + 4) * 4 + (slot & 3);
        azi_c[a0] = pav * zi0; azi_c[a1] = pav * zi1;
        azj_c[a0] = pav * zj0; azj_c[a1] = pav * zj1;
    }
    int p1c = 4 * GP - np;
    if (e < 4) {
        int psl = (e < p1c) ? (np + e) : (4 * GP + 64 - np + (e - p1c));
        size_t a0 = ((size_t)(bh * 17 + (psl >> 2)) * NN + n0 + w) * 4 + (psl & 3);
        size_t a1 = ((size_t)(bh * 17 + (psl >> 2)) * NN + n0 + w + 4) * 4 + (psl & 3);
        azi_c[a0] = 0.f; azi_c[a1] = 0.f;
        azj_c[a0] = 0.f; azj_c[a1] = 0.f;
    }
}

// ---------------------------------------------------------------------------
// attn10: [128 i][32 j], 512 threads, grid = 8bh x 4is x 16js = 512 blocks.
// Chunk-major LDS (conflict-free per-lane b128); ph1 c-outer/j-inner, 2 rows
// per lane; ph3 readlane PV. 3 barriers. 16 waves/CU.
// ---------------------------------------------------------------------------
#define AZIC 0        // [17][128] float4 = 8704 floats
#define ZJC  8704     // [17][32] float4  = 2176
#define HSo  10880    // [32][64]         = 2048
#define ADJo 12928    // [32]
#define EPo  12960    // [32][132]        = 4224
// total 17184 floats = 68.7 KB
__global__ __launch_bounds__(512, 4) void attn10(
    const float* __restrict__ h_ws, const float* __restrict__ azi_c,
    const float* __restrict__ azj_c, const float* __restrict__ adi_ws,
    const float* __restrict__ adj_ws, const float* __restrict__ a,
    float* __restrict__ pacc, float* __restrict__ pm, float* __restrict__ ps)
{
    int blk = blockIdx.x;
    int js = blk & 15, is_ = (blk >> 4) & 3, bh = blk >> 6;
    int i0 = is_ << 7, j0 = js << 5, hh = bh & 3;
    int t = threadIdx.x, lane = t & 63, w = t >> 6;

    __shared__ float smem[17184];

    // ---- stage: azi chunks (rows i0..i0+127), zj chunks, h, adj ----
    {
        float4* dstA = (float4*)(smem + AZIC);
        #pragma unroll
        for (int k = 0; k < 5; ++k) {
            int idx = t + 512 * k;                 // 2176 float4
            if (idx < 2176) {
                int c = idx >> 7, r = idx & 127;
                dstA[idx] = ((const float4*)azi_c)[(size_t)(bh * 17 + c) * NN + i0 + r];
            }
        }
        float4* dstJ = (float4*)(smem + ZJC);
        #pragma unroll
        for (int k = 0; k < 2; ++k) {
            int idx = t + 512 * k;                 // 544 float4
            if (idx < 544) {
                int c = idx >> 5, r = idx & 31;
                dstJ[idx] = ((const float4*)azj_c)[(size_t)(bh * 17 + c) * NN + j0 + r];
            }
        }
        ((float4*)(smem + HSo))[t] =
            ((const float4*)(h_ws + ((size_t)bh * NN + j0) * DD))[t];
        if (t < 32) smem[ADJo + t] = adj_ws[bh * NN + j0 + t];
    }

    float av_e = a[hh * DD + lane];
    unsigned long long mask = __ballot(av_e >= 0.f);
    int GP = (__popcll(mask) + 3) >> 2;

    float adi0 = adi_ws[bh * NN + i0 + lane];
    float adi1 = adi_ws[bh * NN + i0 + 64 + lane];

    __syncthreads();

    // ---- phase 1: scores. wave w -> j = 4w..4w+3; lane = rows (lane, lane+64)
    {
        float accA[4] = {0.f, 0.f, 0.f, 0.f};
        float accB[4] = {0.f, 0.f, 0.f, 0.f};
        const float4* AZ = (const float4*)(smem + AZIC);
        const float4* ZJ = (const float4*)(smem + ZJC);
        #pragma unroll
        for (int c = 0; c < 17; ++c) {
            float4 zA = AZ[c * 128 + lane];          // consecutive b128, full rate
            float4 zB = AZ[c * 128 + 64 + lane];
            float sg = (c < GP) ? 0.4f : -0.4f;
            #pragma unroll
            for (int j4 = 0; j4 < 4; ++j4) {
                float4 zj = ZJ[c * 32 + 4 * w + j4]; // uniform b128
                accA[j4] = fmaf(sg, __builtin_fabsf(zA.x + zj.x), accA[j4]);
                accA[j4] = fmaf(sg, __builtin_fabsf(zA.y + zj.y), accA[j4]);
                accA[j4] = fmaf(sg, __builtin_fabsf(zA.z + zj.z), accA[j4]);
                accA[j4] = fmaf(sg, __builtin_fabsf(zA.w + zj.w), accA[j4]);
                accB[j4] = fmaf(sg, __builtin_fabsf(zB.x + zj.x), accB[j4]);
                accB[j4] = fmaf(sg, __builtin_fabsf(zB.y + zj.y), accB[j4]);
                accB[j4] = fmaf(sg, __builtin_fabsf(zB.z + zj.z), accB[j4]);
                accB[j4] = fmaf(sg, __builtin_fabsf(zB.w + zj.w), accB[j4]);
            }
        }
        #pragma unroll
        for (int j4 = 0; j4 < 4; ++j4) {
            float adjv = smem[ADJo + 4 * w + j4];
            smem[EPo + (4 * w + j4) * 132 + lane]      = adi0 + adjv + accA[j4];
            smem[EPo + (4 * w + j4) * 132 + 64 + lane] = adi1 + adjv + accB[j4];
        }
    }
    __syncthreads();

    // ---- phase 2: softmax. 512 thr: row r = t>>2, quarter jq = t&3 (8 j each)
    {
        int r = t >> 2, jq = t & 3;
        float e8[8];
        float m = -1e30f;
        #pragma unroll
        for (int jj = 0; jj < 8; ++jj) {
            e8[jj] = smem[EPo + (8 * jq + jj) * 132 + r];
            m = fmaxf(m, e8[jj]);
        }
        m = fmaxf(m, __shfl_xor(m, 1));
        m = fmaxf(m, __shfl_xor(m, 2));
        float s = 0.f;
        #pragma unroll
        for (int jj = 0; jj < 8; ++jj) {
            float p = __expf(e8[jj] - m);
            s += p;
            smem[EPo + (8 * jq + jj) * 132 + r] = p;
        }
        s += __shfl_xor(s, 1);
        s += __shfl_xor(s, 2);
        if (jq == 0) {
            pm[js * 4096 + bh * NN + i0 + r] = m;
            ps[js * 4096 + bh * NN + i0 + r] = s;
        }
    }
    __syncthreads();

    // ---- phase 3: PV. wave w -> rows 16w..16w+15; lane = d; readlane p ----
    {
        float acc[16];
        #pragma unroll
        for (int ii = 0; ii < 16; ++ii) acc[ii] = 0.f;
        #pragma unroll 4
        for (int j = 0; j < 32; ++j) {
            float vh = smem[HSo + j * 64 + lane];
            float vp = smem[EPo + j * 132 + 16 * w + (lane & 15)];
            #pragma unroll
            for (int ii = 0; ii < 16; ++ii)
                acc[ii] = fmaf(rdlane(vp, ii), vh, acc[ii]);
        }
        float* pb = pacc + ((size_t)(js * 8 + bh) * NN + i0 + 16 * w) * DD + lane;
        #pragma unroll
        for (int ii = 0; ii < 16; ++ii)
            pb[(size_t)ii * DD] = acc[ii];
    }
}

// ---------------------------------------------------------------------------
// combine 16 j-splits + bias (validated r12-r18). grid = 1024 x 256.
// ---------------------------------------------------------------------------
__global__ __launch_bounds__(256) void combine_kernel(
    const float* __restrict__ pacc, const float* __restrict__ pm,
    const float* __restrict__ ps, const float* __restrict__ bias_param,
    float* __restrict__ out)
{
    int tid = blockIdx.x * 256 + threadIdx.x;
    int d = tid & 63;
    int row = tid >> 6;
    int bh = row >> 9, n = row & 511;
    int b = bh >> 2, hh = bh & 3;
    float mv[16];
    float m = -1e30f;
    #pragma unroll
    for (int p = 0; p < 16; ++p) { mv[p] = pm[p * 4096 + row]; m = fmaxf(m, mv[p]); }
    float denom = 0.f, acc = 0.f;
    #pragma unroll
    for (int p = 0; p < 16; ++p) {
        float wgt = __expf(mv[p] - m);
        denom = fmaf(ps[p * 4096 + row], wgt, denom);
        acc = fmaf(pacc[(size_t)p * 262144 + (size_t)row * 64 + d], wgt, acc);
    }
    out[((size_t)b * NN + n) * (HH * DD) + hh * DD + d] =
        acc / denom + bias_param[hh * DD + d];
}

extern "C" void kernel_launch(void* const* d_in, const int* in_sizes, int n_in,
                              void* d_out, int out_size, void* d_ws, size_t ws_size,
                              hipStream_t stream) {
    const float* x    = (const float*)d_in[0];
    const float* Wp   = (const float*)d_in[1];
    const float* bp   = (const float*)d_in[2];
    const float* Wc   = (const float*)d_in[3];
    const float* Wcb  = (const float*)d_in[4];
    const float* a    = (const float*)d_in[5];
    const float* bpar = (const float*)d_in[6];
    float* out = (float*)d_out;

    float* ws     = (float*)d_ws;
    float* h_ws   = ws;
    float* azi_c  = ws + 262144;
    float* azj_c  = ws + 540672;
    float* adi_ws = ws + 819200;
    float* adj_ws = ws + 823296;
    float* pacc   = ws + 827392;
    float* pm     = ws + 5021696;
    float* ps     = ws + 5087232;

    proj_kernel<<<dim3(512), dim3(256), 0, stream>>>(
        x, Wp, bp, Wc, Wcb, a, h_ws, azi_c, azj_c, adi_ws, adj_ws);
    attn10<<<dim3(512), dim3(512), 0, stream>>>(
        h_ws, azi_c, azj_c, adi_ws, adj_ws, a, pacc, pm, ps);
    combine_kernel<<<dim3(1024), dim3(256), 0, stream>>>(
        pacc, pm, ps, bpar, out);
}